// Round 6
// baseline (161.747 us; speedup 1.0000x reference)
//
#include <hip/hip_runtime.h>
#include <cmath>

// SSIM fused kernel for B=16, C=3, H=W=512 fp32 images.
// R6 = R5's V-first + 2-col H-phase + split-float2 LDS, with the spill
// fixed and a finer grid.
// R5 post-mortem: VGPR hit the 128 cap, 11 MB scratch spill, occ 20%.
// Fixes:
//  - NO rSP ring: ring holds only raw (a,b) (22 floats, -22 VGPR, the
//    spill margin). sq/pr recomputed per tap in V-conv (+5 VALU/tap; we
//    have VALU headroom: R4/R5 measured 31-35% busy).
//  - STRIPE 32 -> 16: 1536 blocks = 6 blocks/CU (R2's occupancy 43% was
//    GRID-limited at 768 blocks). Halo rows are ~free in V-first.
// Kept from R5 (the correct parts):
//  - split float2 arrays abL/spL -> H-phase reads are DENSE stride-16B
//    ds_read_b128 (12 per 2 cols vs 22 b64), conflict-free; a merged
//    float4 layout would be stride-32B = half the banks = 2x read cycles.
//  - 2 output rows per iteration, waves 0-3 row A / 4-7 row B
//    (wave-uniform sel); one barrier per pair (8/block); double buffer.
// Sentinels: WRITE_SIZE ~30 KB (no spill), VGPR <= 100, conflicts ~0.

#define IMG_H 512
#define IMG_W 512
#define STRIPE 16
#define NSTR (IMG_H / STRIPE)      // 32
#define NPLANES 48                 // 16*3
#define NBLOCKS (NPLANES * NSTR)   // 1536
#define SROWS (STRIPE + 10)        // 26 staged rows
#define NPAIRS (SROWS / 2)         // 13
#define SSIM_C1 (0.01f * 0.01f)
#define SSIM_C2 (0.03f * 0.03f)

typedef float f32x2 __attribute__((ext_vector_type(2)));

struct W2x11 { float2 w[11]; };   // pre-broadcast {w,w} pairs

__launch_bounds__(512, 2)
__global__ void ssim_main(const float* __restrict__ img1,
                          const float* __restrict__ img2,
                          float* __restrict__ blockSums, W2x11 wv) {
    // slot s holds V-filtered col (x0-5+s); [dbuf][row-of-pair][slot]
    __shared__ __align__(16) float2 abL[2][2][528];
    __shared__ __align__(16) float2 spL[2][2][528];
    __shared__ float red[8];

    const int x = threadIdx.x;            // 0..511, one column for V-phase
    const int bid = blockIdx.x;
    const int plane = bid >> 5;           // /NSTR
    const int stripe = bid & (NSTR - 1);
    const int y0 = stripe * STRIPE;
    const size_t base = (size_t)plane * (IMG_H * IMG_W);

    // zero halo pads (slots 0..4 and 517..521; all dbuf x row arrays).
    // Ordered before first read by the p=5 barrier.
    if (x < 10) {
        const int col = (x < 5) ? x : (x + 512);
#pragma unroll
        for (int d = 0; d < 2; ++d)
#pragma unroll
            for (int r = 0; r < 2; ++r) {
                abL[d][r][col] = make_float2(0.f, 0.f);
                spL[d][r][col] = make_float2(0.f, 0.f);
            }
    }

    // vertical ring of RAW (a,b) only, static-indexed via unroll
    f32x2 rAB[11];
    float acc = 0.f;

    // preload staged rows 0,1 (image rows y0-5, y0-4)
    float pa0 = 0.f, pb0 = 0.f, pa1 = 0.f, pb1 = 0.f;
    {
        const int r0 = y0 - 5, r1 = y0 - 4;
        if (r0 >= 0) {
            pa0 = img1[base + (size_t)r0 * IMG_W + x];
            pb0 = img2[base + (size_t)r0 * IMG_W + x];
        }
        if (r1 >= 0) {
            pa1 = img1[base + (size_t)r1 * IMG_W + x];
            pb1 = img2[base + (size_t)r1 * IMG_W + x];
        }
    }

    int buf = 0;
#pragma unroll 1
    for (int c = 0; c < 2; ++c) {
#pragma unroll
        for (int jp = 0; jp < 11; ++jp) {
            const int p = c * 11 + jp;     // pair index; staged rows 2p,2p+1
            if (p < NPAIRS) {              // compile-time per (c,jp)
                // push raw row 2p
                {
                    f32x2 ab; ab.x = pa0; ab.y = pb0;
                    rAB[(2 * jp) % 11] = ab;
                }
                if (p >= 5) {  // V-conv for staged row 2p (ring full)
                    f32x2 vAB = {0.f, 0.f};
                    float vS = 0.f, vP = 0.f;
#pragma unroll
                    for (int k = 0; k < 11; ++k) {
                        const int s = (2 * jp + 1 + k) % 11;   // static
                        const f32x2 ab = rAB[s];
                        f32x2 w2; w2.x = wv.w[k].x; w2.y = wv.w[k].y;
                        vAB = __builtin_elementwise_fma(w2, ab, vAB);
                        const float sq = fmaf(ab.y, ab.y, ab.x * ab.x);
                        const float pr = ab.x * ab.y;
                        vS = fmaf(wv.w[k].x, sq, vS);
                        vP = fmaf(wv.w[k].x, pr, vP);
                    }
                    abL[buf][0][x + 5] = make_float2(vAB.x, vAB.y);
                    spL[buf][0][x + 5] = make_float2(vS, vP);
                }
                // push raw row 2p+1
                {
                    f32x2 ab; ab.x = pa1; ab.y = pb1;
                    rAB[(2 * jp + 1) % 11] = ab;
                }
                if (p >= 5) {  // V-conv for staged row 2p+1
                    f32x2 vAB = {0.f, 0.f};
                    float vS = 0.f, vP = 0.f;
#pragma unroll
                    for (int k = 0; k < 11; ++k) {
                        const int s = (2 * jp + 2 + k) % 11;   // static
                        const f32x2 ab = rAB[s];
                        f32x2 w2; w2.x = wv.w[k].x; w2.y = wv.w[k].y;
                        vAB = __builtin_elementwise_fma(w2, ab, vAB);
                        const float sq = fmaf(ab.y, ab.y, ab.x * ab.x);
                        const float pr = ab.x * ab.y;
                        vS = fmaf(wv.w[k].x, sq, vS);
                        vP = fmaf(wv.w[k].x, pr, vP);
                    }
                    abL[buf][1][x + 5] = make_float2(vAB.x, vAB.y);
                    spL[buf][1][x + 5] = make_float2(vS, vP);
                }
                // prefetch staged rows 2p+2, 2p+3 (consumed next iter)
                pa0 = 0.f; pb0 = 0.f; pa1 = 0.f; pb1 = 0.f;
                if (p + 1 < NPAIRS) {
                    const int rn0 = y0 - 5 + 2 * (p + 1);
                    const int rn1 = rn0 + 1;
                    if (rn0 >= 0 && rn0 < IMG_H) {
                        pa0 = img1[base + (size_t)rn0 * IMG_W + x];
                        pb0 = img2[base + (size_t)rn0 * IMG_W + x];
                    }
                    if (rn1 >= 0 && rn1 < IMG_H) {
                        pa1 = img1[base + (size_t)rn1 * IMG_W + x];
                        pb1 = img2[base + (size_t)rn1 * IMG_W + x];
                    }
                }
                if (p >= 5) {
                    __syncthreads();
                    // H-phase: waves 0-3 -> row 2p, waves 4-7 -> row 2p+1;
                    // each thread does cols 2u, 2u+1.
                    const int sel = x >> 8;        // wave-uniform
                    const int u = x & 255;
                    const float2* Ap = abL[buf][sel];
                    const float2* Sp = spL[buf][sel];
                    f32x2 hAB0 = {0.f, 0.f}, hAB1 = {0.f, 0.f};
                    f32x2 hSP0 = {0.f, 0.f}, hSP1 = {0.f, 0.f};
#pragma unroll
                    for (int m = 0; m < 6; ++m) {  // 6 dense b128 per array
                        const float4 q = *(const float4*)(&Ap[2 * u + 2 * m]);
                        f32x2 lo; lo.x = q.x; lo.y = q.y;   // slot 2u+2m
                        f32x2 hi; hi.x = q.z; hi.y = q.w;   // slot 2u+2m+1
                        f32x2 w2;
                        // col 2u: slot 2u+2m -> tap 2m; +1 -> tap 2m+1
                        w2.x = wv.w[2 * m].x; w2.y = wv.w[2 * m].y;
                        hAB0 = __builtin_elementwise_fma(w2, lo, hAB0);
                        hAB1 = __builtin_elementwise_fma(w2, hi, hAB1); // col 2u+1 tap 2m
                        if (2 * m + 1 <= 10) {
                            w2.x = wv.w[2 * m + 1].x; w2.y = wv.w[2 * m + 1].y;
                            hAB0 = __builtin_elementwise_fma(w2, hi, hAB0);
                        }
                        if (2 * m - 1 >= 0) {      // col 2u+1: slot 2u+2m -> tap 2m-1
                            w2.x = wv.w[2 * m - 1].x; w2.y = wv.w[2 * m - 1].y;
                            hAB1 = __builtin_elementwise_fma(w2, lo, hAB1);
                        }
                    }
#pragma unroll
                    for (int m = 0; m < 6; ++m) {
                        const float4 q = *(const float4*)(&Sp[2 * u + 2 * m]);
                        f32x2 lo; lo.x = q.x; lo.y = q.y;
                        f32x2 hi; hi.x = q.z; hi.y = q.w;
                        f32x2 w2;
                        w2.x = wv.w[2 * m].x; w2.y = wv.w[2 * m].y;
                        hSP0 = __builtin_elementwise_fma(w2, lo, hSP0);
                        hSP1 = __builtin_elementwise_fma(w2, hi, hSP1);
                        if (2 * m + 1 <= 10) {
                            w2.x = wv.w[2 * m + 1].x; w2.y = wv.w[2 * m + 1].y;
                            hSP0 = __builtin_elementwise_fma(w2, hi, hSP0);
                        }
                        if (2 * m - 1 >= 0) {
                            w2.x = wv.w[2 * m - 1].x; w2.y = wv.w[2 * m - 1].y;
                            hSP1 = __builtin_elementwise_fma(w2, lo, hSP1);
                        }
                    }
                    // epilogue for col 2u
                    {
                        const float vA = hAB0.x, vB = hAB0.y;
                        const float vS = hSP0.x, vP = hSP0.y;
                        const float mu11 = vA * vA, mu22 = vB * vB;
                        const float mu12 = vA * vB;
                        const float num = fmaf(2.f, mu12, SSIM_C1) *
                                          fmaf(2.f, vP - mu12, SSIM_C2);
                        const float d1  = mu11 + mu22;
                        const float den = (d1 + SSIM_C1) * ((vS - d1) + SSIM_C2);
                        acc = fmaf(num, __builtin_amdgcn_rcpf(den), acc);
                    }
                    // epilogue for col 2u+1
                    {
                        const float vA = hAB1.x, vB = hAB1.y;
                        const float vS = hSP1.x, vP = hSP1.y;
                        const float mu11 = vA * vA, mu22 = vB * vB;
                        const float mu12 = vA * vB;
                        const float num = fmaf(2.f, mu12, SSIM_C1) *
                                          fmaf(2.f, vP - mu12, SSIM_C2);
                        const float d1  = mu11 + mu22;
                        const float den = (d1 + SSIM_C1) * ((vS - d1) + SSIM_C2);
                        acc = fmaf(num, __builtin_amdgcn_rcpf(den), acc);
                    }
                    buf ^= 1;
                }
            }
        }
    }

    // block reduction: wave shuffle, then 8 wave-sums via LDS
#pragma unroll
    for (int off = 32; off >= 1; off >>= 1)
        acc += __shfl_down(acc, off, 64);
    const int wave = x >> 6, lane = x & 63;
    if (lane == 0) red[wave] = acc;
    __syncthreads();
    if (x == 0) {
        float s = 0.f;
#pragma unroll
        for (int k = 0; k < 8; ++k) s += red[k];
        blockSums[bid] = s;
    }
}

__global__ void ssim_reduce(const float* __restrict__ bs,
                            float* __restrict__ out) {
    __shared__ double red[4];
    const int t = threadIdx.x;  // 256 threads
    double a = 0.0;
    for (int idx = t; idx < NBLOCKS; idx += 256) a += (double)bs[idx];
#pragma unroll
    for (int off = 32; off >= 1; off >>= 1)
        a += __shfl_down(a, off, 64);
    const int wave = t >> 6, lane = t & 63;
    if (lane == 0) red[wave] = a;
    __syncthreads();
    if (t == 0) {
        const double s = red[0] + red[1] + red[2] + red[3];
        out[0] = (float)(s / (double)((double)NPLANES * IMG_H * IMG_W));
    }
}

extern "C" void kernel_launch(void* const* d_in, const int* in_sizes, int n_in,
                              void* d_out, int out_size, void* d_ws, size_t ws_size,
                              hipStream_t stream) {
    const float* img1 = (const float*)d_in[0];
    const float* img2 = (const float*)d_in[1];
    float* out = (float*)d_out;
    float* bs = (float*)d_ws;   // 1536 floats of scratch

    // Gaussian weights, faithful to reference: center 5.5, sigma 1.5
    W2x11 wv;
    double g[11], s = 0.0;
    for (int i = 0; i < 11; ++i) {
        const double d = (double)i - 5.5;
        g[i] = exp(-(d * d) / (2.0 * 1.5 * 1.5));
        s += g[i];
    }
    for (int i = 0; i < 11; ++i) {
        const float w = (float)(g[i] / s);
        wv.w[i] = make_float2(w, w);
    }

    ssim_main<<<NBLOCKS, 512, 0, stream>>>(img1, img2, bs, wv);
    ssim_reduce<<<1, 256, 0, stream>>>(bs, out);
}

// Round 7
// 156.060 us; speedup vs baseline: 1.0364x; 1.0364x over previous
//
#include <hip/hip_runtime.h>
#include <cmath>

// SSIM fused kernel for B=16, C=3, H=W=512 fp32 images.
// R7: BARRIER-FREE wave-private tiles on the proven R2 algorithm.
// History: R2 (H-first, 512thr, 44-float ring, VGPR 36) = 65us, VALU 72%,
// ~28% idle. R4/R5/R6 proved: shifting work to LDS pipe loses (R4), VGPR
// >128 spills (R5), VGPR >64 halves wave residency (R6). R2's idle is the
// 42 __syncthreads/block: 8 waves converge every staged row with only ~3
// blocks/CU of foreign work to fill the bubble.
// Fix: the row buffer becomes WAVE-PRIVATE (wbuf[8][76]). Each wave owns
// 64 output cols; lanes 0-9 fetch the 10 halo cols via masked extra
// global loads (cheap: HBM at 12%, halo re-reads hit L2/L3). Within one
// wave, ds_write -> lgkmcnt -> ds_read is program-ordered: NO barriers in
// the main loop (42 -> 0). Arithmetic identical to R2 (absmax was 0.0).
// Sentinels: VGPR <= 64 (residency cliff), WRITE_SIZE ~24KB (no spill),
// conflicts ~0 (row stride 76 float2, consecutive-lane b64 reads).

#define IMG_H 512
#define IMG_W 512
#define STRIPE 32
#define NSTR (IMG_H / STRIPE)      // 16
#define NPLANES 48                 // 16*3
#define NBLOCKS (NPLANES * NSTR)   // 768  (= 3 blocks/CU exactly)
#define SSIM_C1 (0.01f * 0.01f)
#define SSIM_C2 (0.03f * 0.03f)

typedef float f32x2 __attribute__((ext_vector_type(2)));

struct W2x11 { float2 w[11]; };   // pre-broadcast {w,w} pairs

__launch_bounds__(512, 2)
__global__ void ssim_main(const float* __restrict__ img1,
                          const float* __restrict__ img2,
                          float* __restrict__ blockSums, W2x11 wvp) {
    // per-wave row buffer: slots 0..73 hold cols (64*wave -5 .. +68)
    __shared__ float2 wbuf[8][76];
    __shared__ float red[8];

    const int x = threadIdx.x;            // 0..511, output col x
    const int wid = x >> 6;               // wave 0..7
    const int lane = x & 63;
    const int bid = blockIdx.x;
    const int plane = bid >> 4;           // /NSTR
    const int stripe = bid & (NSTR - 1);
    const int y0 = stripe * STRIPE;
    const size_t base = (size_t)plane * (IMG_H * IMG_W);

    // halo mapping: lanes 0..4 -> left halo cols 64w-5..64w-1 (slots 0..4),
    // lanes 5..9 -> right halo cols 64w+64..64w+68 (slots 69..73)
    const bool hlane = (lane < 10);
    const int hc = (wid << 6) + ((lane < 5) ? (lane - 5) : (lane + 59));
    const bool hok = hlane && (hc >= 0) && (hc < IMG_W);
    const int hslot = (lane < 5) ? lane : (lane + 64);
    const int hcc = hok ? hc : 0;         // safe address

    // ring of H-FILTERED values: (hA,hB) and (hS,hP) packed pairs
    f32x2 rAB[11], rSP[11];
    float acc = 0.f;

    // prefetch first staged row (r = y0-5)
    float pa = 0.f, pb = 0.f, qa = 0.f, qb = 0.f;
    {
        const int r0 = y0 - 5;
        if (r0 >= 0) {
            const size_t rb = base + (size_t)r0 * IMG_W;
            pa = img1[rb + x];
            pb = img2[rb + x];
            if (hok) { qa = img1[rb + hcc]; qb = img2[rb + hcc]; }
        }
    }

#pragma unroll 1
    for (int c = 0; c < 4; ++c) {
#pragma unroll
        for (int j = 0; j < 11; ++j) {
            const int i = c * 11 + j;      // staged row 0..43; work for i<42
            if (i < 42) {                  // compile-time per (c,j)
                // stage current row into the wave-private buffer
                wbuf[wid][lane + 5] = make_float2(pa, pb);
                if (hlane) wbuf[wid][hslot] = make_float2(qa, qb);
                // prefetch next row (overlaps with conv below)
                pa = 0.f; pb = 0.f; qa = 0.f; qb = 0.f;
                const int rn = y0 - 4 + i;
                if (i + 1 < 42 && rn >= 0 && rn < IMG_H) {
                    const size_t rb = base + (size_t)rn * IMG_W;
                    pa = img1[rb + x];
                    pb = img2[rb + x];
                    if (hok) { qa = img1[rb + hcc]; qb = img2[rb + hcc]; }
                }
                // NO barrier: same-wave ds_write -> ds_read is ordered by
                // lgkmcnt; taps for col x are slots lane..lane+10.
                f32x2 hAB = {0.f, 0.f}, hSP = {0.f, 0.f};
#pragma unroll
                for (int k = 0; k < 11; ++k) {
                    const float2 t = wbuf[wid][lane + k];   // ds_read_b64
                    f32x2 ab; ab.x = t.x; ab.y = t.y;
                    f32x2 sp;
                    sp.x = fmaf(t.y, t.y, t.x * t.x);  // a^2+b^2
                    sp.y = t.x * t.y;                  // a*b
                    f32x2 w2; w2.x = wvp.w[k].x; w2.y = wvp.w[k].y;
                    hAB = __builtin_elementwise_fma(w2, ab, hAB);
                    hSP = __builtin_elementwise_fma(w2, sp, hSP);
                }
                rAB[j] = hAB; rSP[j] = hSP;

                if (i >= 10) {  // output row y = y0 + i - 10
                    f32x2 vAB = {0.f, 0.f}, vSP = {0.f, 0.f};
#pragma unroll
                    for (int k = 0; k < 11; ++k) {
                        const int s = (j + 1 + k) % 11;  // static per (j,k)
                        f32x2 w2; w2.x = wvp.w[k].x; w2.y = wvp.w[k].y;
                        vAB = __builtin_elementwise_fma(w2, rAB[s], vAB);
                        vSP = __builtin_elementwise_fma(w2, rSP[s], vSP);
                    }
                    const float vA = vAB.x, vB = vAB.y;
                    const float vS = vSP.x, vP = vSP.y;
                    const float mu11 = vA * vA;
                    const float mu22 = vB * vB;
                    const float mu12 = vA * vB;
                    const float num = fmaf(2.f, mu12, SSIM_C1) *
                                      fmaf(2.f, vP - mu12, SSIM_C2);
                    const float d1  = mu11 + mu22;
                    const float den = (d1 + SSIM_C1) * ((vS - d1) + SSIM_C2);
                    acc = fmaf(num, __builtin_amdgcn_rcpf(den), acc);
                }
            }
        }
    }

    // block reduction: wave shuffle, then 8 wave-sums via LDS
#pragma unroll
    for (int off = 32; off >= 1; off >>= 1)
        acc += __shfl_down(acc, off, 64);
    if (lane == 0) red[wid] = acc;
    __syncthreads();
    if (x == 0) {
        float s = 0.f;
#pragma unroll
        for (int k = 0; k < 8; ++k) s += red[k];
        blockSums[bid] = s;
    }
}

__global__ void ssim_reduce(const float* __restrict__ bs,
                            float* __restrict__ out) {
    __shared__ double red[4];
    const int t = threadIdx.x;  // 256 threads
    double a = 0.0;
    for (int idx = t; idx < NBLOCKS; idx += 256) a += (double)bs[idx];
#pragma unroll
    for (int off = 32; off >= 1; off >>= 1)
        a += __shfl_down(a, off, 64);
    const int wave = t >> 6, lane = t & 63;
    if (lane == 0) red[wave] = a;
    __syncthreads();
    if (t == 0) {
        const double s = red[0] + red[1] + red[2] + red[3];
        out[0] = (float)(s / (double)((double)NPLANES * IMG_H * IMG_W));
    }
}

extern "C" void kernel_launch(void* const* d_in, const int* in_sizes, int n_in,
                              void* d_out, int out_size, void* d_ws, size_t ws_size,
                              hipStream_t stream) {
    const float* img1 = (const float*)d_in[0];
    const float* img2 = (const float*)d_in[1];
    float* out = (float*)d_out;
    float* bs = (float*)d_ws;   // 768 floats of scratch

    // Gaussian weights, faithful to reference: center 5.5, sigma 1.5
    W2x11 wv;
    double g[11], s = 0.0;
    for (int i = 0; i < 11; ++i) {
        const double d = (double)i - 5.5;
        g[i] = exp(-(d * d) / (2.0 * 1.5 * 1.5));
        s += g[i];
    }
    for (int i = 0; i < 11; ++i) {
        const float w = (float)(g[i] / s);
        wv.w[i] = make_float2(w, w);
    }

    ssim_main<<<NBLOCKS, 512, 0, stream>>>(img1, img2, bs, wv);
    ssim_reduce<<<1, 256, 0, stream>>>(bs, out);
}